// Round 11
// baseline (306.791 us; speedup 1.0000x reference)
//
#include <hip/hip_runtime.h>

typedef unsigned short u16;
typedef float f32x4 __attribute__((ext_vector_type(4)));
typedef short short8 __attribute__((ext_vector_type(8)));
typedef __bf16 bf16x8 __attribute__((ext_vector_type(8)));

#define B_  4
#define S_  512
#define D_  512
#define H_  8
#define HD_ 64
#define V_  32000
#define NSHARD_ 64
#define CAP_ 128
#define TOK_ (B_ * S_)

__device__ __forceinline__ float bf2f(u16 u) { return __uint_as_float(((unsigned)u) << 16); }
__device__ __forceinline__ u16 f2bf(float f) {
  unsigned u = __float_as_uint(f);
  u += 0x7FFFu + ((u >> 16) & 1u);
  return (u16)(u >> 16);
}

__device__ __forceinline__ f32x4 mfma16(short8 a, short8 b, f32x4 c) {
  return __builtin_amdgcn_mfma_f32_16x16x32_bf16(
      __builtin_bit_cast(bf16x8, a), __builtin_bit_cast(bf16x8, b), c, 0, 0, 0);
}

__device__ __forceinline__ void load_lds16(const void* g, void* l) {
  __builtin_amdgcn_global_load_lds(
      (const __attribute__((address_space(1))) void*)g,
      (__attribute__((address_space(3))) void*)l, 16, 0, 0);
}

// ---------------------------------------------------------------------------
// Unified GEMM: all operands bf16, (rows, K) row-major ("BT" layout).
// NS: 1 = hi only; 3 = hi+lo pairs (3 MFMAs, ~f32 accuracy).
// OM: 0 = f32 out; 1 = split bf16 pair out.
// ---------------------------------------------------------------------------
template<int NS, int OM>
__global__ __launch_bounds__(256) void gemm_bt(
    const u16* __restrict__ Ah, const u16* __restrict__ Al, int ldA,
    const u16* __restrict__ Bh, const u16* __restrict__ Bl, int ldB,
    void* __restrict__ C0, void* __restrict__ C1, int ldC,
    int K)
{
  __shared__ u16 AsH[64 * 64];
  __shared__ u16 BsH[64 * 64];
  __shared__ u16 AsL[(NS == 3) ? 64 * 64 : 8];
  __shared__ u16 BsL[(NS == 3) ? 64 * 64 : 8];

  const int n0 = blockIdx.x * 64;
  const int m0 = blockIdx.y * 64;

  const int tid = threadIdx.x;
  const int lane = tid & 63;
  const int w = tid >> 6;
  const int wm = (w >> 1) * 32, wn = (w & 1) * 32;
  const int fr = lane & 15, kg = lane >> 4;

  const int srow = lane >> 3;
  const int schunk = (lane & 7) ^ srow;

  const u16* gAh = Ah + (long)(m0 + w * 16 + srow) * ldA + schunk * 8;
  const u16* gBh = Bh + (long)(n0 + w * 16 + srow) * ldB + schunk * 8;
  const u16* gAl = (NS == 3) ? (Al + (long)(m0 + w * 16 + srow) * ldA + schunk * 8) : nullptr;
  const u16* gBl = (NS == 3) ? (Bl + (long)(n0 + w * 16 + srow) * ldB + schunk * 8) : nullptr;
  u16* lAh = &AsH[(w * 16) * 64];
  u16* lBh = &BsH[(w * 16) * 64];
  u16* lAl = &AsL[(NS == 3) ? (w * 16) * 64 : 0];
  u16* lBl = &BsL[(NS == 3) ? (w * 16) * 64 : 0];

  f32x4 acc[2][2] = {};

  for (int k0 = 0; k0 < K; k0 += 64) {
    load_lds16(gAh + k0, lAh);
    load_lds16(gAh + k0 + 8 * ldA, lAh + 8 * 64);
    load_lds16(gBh + k0, lBh);
    load_lds16(gBh + k0 + 8 * ldB, lBh + 8 * 64);
    if (NS == 3) {
      load_lds16(gAl + k0, lAl);
      load_lds16(gAl + k0 + 8 * ldA, lAl + 8 * 64);
      load_lds16(gBl + k0, lBl);
      load_lds16(gBl + k0 + 8 * ldB, lBl + 8 * 64);
    }
    __syncthreads();

    short8 ah[2][2], bh[2][2], al[2][2], bl[2][2];
#pragma unroll
    for (int mi = 0; mi < 2; ++mi) {
      int row = wm + mi * 16 + fr;
#pragma unroll
      for (int ks = 0; ks < 2; ++ks) {
        int idx = row * 64 + ((ks * 32 + kg * 8) ^ ((fr & 7) << 3));
        ah[mi][ks] = *(const short8*)&AsH[idx];
        if (NS == 3) al[mi][ks] = *(const short8*)&AsL[idx];
      }
    }
#pragma unroll
    for (int ni = 0; ni < 2; ++ni) {
      int row = wn + ni * 16 + fr;
#pragma unroll
      for (int ks = 0; ks < 2; ++ks) {
        int idx = row * 64 + ((ks * 32 + kg * 8) ^ ((fr & 7) << 3));
        bh[ni][ks] = *(const short8*)&BsH[idx];
        if (NS == 3) bl[ni][ks] = *(const short8*)&BsL[idx];
      }
    }
#pragma unroll
    for (int ks = 0; ks < 2; ++ks)
#pragma unroll
      for (int mi = 0; mi < 2; ++mi)
#pragma unroll
        for (int ni = 0; ni < 2; ++ni) {
          acc[mi][ni] = mfma16(ah[mi][ks], bh[ni][ks], acc[mi][ni]);
          if (NS == 3) {
            acc[mi][ni] = mfma16(ah[mi][ks], bl[ni][ks], acc[mi][ni]);
            acc[mi][ni] = mfma16(al[mi][ks], bh[ni][ks], acc[mi][ni]);
          }
        }
    __syncthreads();
  }

#pragma unroll
  for (int mi = 0; mi < 2; ++mi)
#pragma unroll
    for (int ni = 0; ni < 2; ++ni) {
      int gnc = n0 + wn + ni * 16 + fr;
#pragma unroll
      for (int r = 0; r < 4; ++r) {
        int gm = m0 + wm + mi * 16 + kg * 4 + r;
        float v = acc[mi][ni][r];
        long idx = (long)gm * ldC + gnc;
        if (OM == 0) {
          ((float*)C0)[idx] = v;
        } else {
          u16 h = f2bf(v);
          ((u16*)C0)[idx] = h;
          ((u16*)C1)[idx] = f2bf(v - bf2f(h));
        }
      }
    }
}

// ---------------------------------------------------------------------------
// FUSED flash attention: per (q-block mb, z=b*8+h): S = qk^T/8 (causal),
// online softmax, O = P@V / l. 4 waves x 16 rows; P staged via wave-private
// XOR-swizzled LDS (C-frag -> A-frag layout change); output = oh/ol pair.
// ---------------------------------------------------------------------------
__global__ __launch_bounds__(256) void attn_k(
    const u16* __restrict__ qkvh, const u16* __restrict__ qkvl,
    const u16* __restrict__ vTh, const u16* __restrict__ vTl,
    u16* __restrict__ oh, u16* __restrict__ ol)
{
  const int mb = blockIdx.x;
  const int z = blockIdx.y;             // b*8+h
  const int b = z >> 3, h = z & 7;
  const int m0 = mb * 64;
  const long qbase = (long)b * 512 * 1536 + h * 64;
  const long kbase = qbase + 512;
  const long vbase = (long)z * 64 * 512;

  const int tid = threadIdx.x;
  const int lane = tid & 63;
  const int w = tid >> 6;               // wave 0..3: rows w*16..w*16+15
  const int fr = lane & 15, kg = lane >> 4;

  __shared__ u16 p_h[4][16 * 64];
  __shared__ u16 p_l[4][16 * 64];

  // q A-fragments (held for all k-tiles)
  short8 qh_[2], ql_[2];
#pragma unroll
  for (int ks = 0; ks < 2; ++ks) {
    long ra = qbase + (long)(m0 + w * 16 + fr) * 1536 + ks * 32 + kg * 8;
    qh_[ks] = *(const short8*)(qkvh + ra);
    ql_[ks] = *(const short8*)(qkvl + ra);
  }

  f32x4 acc_o[4] = {};
  float m_run[4], l_run[4];
#pragma unroll
  for (int r = 0; r < 4; ++r) { m_run[r] = -3.4e38f; l_run[r] = 0.f; }

  for (int kb = 0; kb <= mb; ++kb) {
    // ---- S-tile (16 rows x 64 cols per wave), 3-MFMA hi/lo
    f32x4 s4[4] = {};
#pragma unroll
    for (int ks = 0; ks < 2; ++ks)
#pragma unroll
      for (int ni = 0; ni < 4; ++ni) {
        long rb = kbase + (long)(kb * 64 + ni * 16 + fr) * 1536 + ks * 32 + kg * 8;
        short8 kh = *(const short8*)(qkvh + rb);
        short8 kl = *(const short8*)(qkvl + rb);
        s4[ni] = mfma16(qh_[ks], kh, s4[ni]);
        s4[ni] = mfma16(qh_[ks], kl, s4[ni]);
        s4[ni] = mfma16(ql_[ks], kh, s4[ni]);
      }
    // mask + scale + row max (rows kg*4+r, cols ni*16+fr; reduce over fr)
    float tmax[4];
#pragma unroll
    for (int r = 0; r < 4; ++r) tmax[r] = -3.4e38f;
#pragma unroll
    for (int ni = 0; ni < 4; ++ni)
#pragma unroll
      for (int r = 0; r < 4; ++r) {
        int row = m0 + w * 16 + kg * 4 + r;
        int col = kb * 64 + ni * 16 + fr;
        float sv = (col <= row) ? s4[ni][r] * 0.125f : -3.4e38f;
        s4[ni][r] = sv;
        tmax[r] = fmaxf(tmax[r], sv);
      }
#pragma unroll
    for (int r = 0; r < 4; ++r)
#pragma unroll
      for (int off = 8; off; off >>= 1)
        tmax[r] = fmaxf(tmax[r], __shfl_xor(tmax[r], off));

    float tsum[4];
#pragma unroll
    for (int r = 0; r < 4; ++r) {
      float mn = fmaxf(m_run[r], tmax[r]);
      float sc = expf(m_run[r] - mn);
      m_run[r] = mn;
      l_run[r] *= sc;
#pragma unroll
      for (int ni = 0; ni < 4; ++ni) acc_o[ni][r] *= sc;
      tsum[r] = 0.f;
    }

    __syncthreads();   // previous iteration's p_lds reads are done
#pragma unroll
    for (int ni = 0; ni < 4; ++ni)
#pragma unroll
      for (int r = 0; r < 4; ++r) {
        float p = expf(s4[ni][r] - m_run[r]);
        tsum[r] += p;
        int rl = kg * 4 + r;
        int chunk = (ni * 2 + (fr >> 3)) ^ (rl & 7);
        int addr = rl * 64 + chunk * 8 + (fr & 7);
        u16 hv = f2bf(p);
        p_h[w][addr] = hv;
        p_l[w][addr] = f2bf(p - bf2f(hv));
      }
#pragma unroll
    for (int r = 0; r < 4; ++r) {
#pragma unroll
      for (int off = 8; off; off >>= 1) tsum[r] += __shfl_xor(tsum[r], off);
      l_run[r] += tsum[r];
    }
    __syncthreads();   // p_lds writes visible

    // ---- PV: A = p (from LDS, A-frag layout), B = vT rows (d, s-contig)
#pragma unroll
    for (int ks = 0; ks < 2; ++ks) {
      int ca = fr * 64 + (((ks * 4 + kg) ^ (fr & 7)) * 8);
      short8 pah = *(const short8*)&p_h[w][ca];
      short8 pal = *(const short8*)&p_l[w][ca];
#pragma unroll
      for (int ni = 0; ni < 4; ++ni) {
        long rv = vbase + (long)(ni * 16 + fr) * 512 + kb * 64 + ks * 32 + kg * 8;
        short8 vh = *(const short8*)(vTh + rv);
        short8 vl = *(const short8*)(vTl + rv);
        acc_o[ni] = mfma16(pah, vh, acc_o[ni]);
        acc_o[ni] = mfma16(pah, vl, acc_o[ni]);
        acc_o[ni] = mfma16(pal, vh, acc_o[ni]);
      }
    }
  }

  // epilogue: O /= l, write split pair (row = b*512+s, col = h*64+d)
#pragma unroll
  for (int ni = 0; ni < 4; ++ni)
#pragma unroll
    for (int r = 0; r < 4; ++r) {
      float ov = acc_o[ni][r] / l_run[r];
      long orow = (long)(b * 512 + m0 + w * 16 + kg * 4 + r);
      long oidx = orow * 512 + h * 64 + ni * 16 + fr;
      u16 hv = f2bf(ov);
      oh[oidx] = hv;
      ol[oidx] = f2bf(ov - bf2f(hv));
    }
}

// ---------------------------------------------------------------------------
// Gate GEMM with fused sigmoid-mix epilogue.
// ---------------------------------------------------------------------------
__global__ __launch_bounds__(256) void gate_gemm_k(
    const u16* __restrict__ Ah, const u16* __restrict__ Bh,
    const float* __restrict__ bgp, const float* __restrict__ ctxf,
    const float* __restrict__ msf, u16* __restrict__ fused)
{
  __shared__ u16 AsH[64 * 64];
  __shared__ u16 BsH[64 * 64];

  const int n0 = blockIdx.x * 64;
  const int m0 = blockIdx.y * 64;
  const int tid = threadIdx.x;
  const int lane = tid & 63;
  const int w = tid >> 6;
  const int wm = (w >> 1) * 32, wn = (w & 1) * 32;
  const int fr = lane & 15, kg = lane >> 4;
  const int srow = lane >> 3;
  const int schunk = (lane & 7) ^ srow;

  const u16* gAh = Ah + (long)(m0 + w * 16 + srow) * 1024 + schunk * 8;
  const u16* gBh = Bh + (long)(n0 + w * 16 + srow) * 1024 + schunk * 8;
  u16* lAh = &AsH[(w * 16) * 64];
  u16* lBh = &BsH[(w * 16) * 64];

  f32x4 acc[2][2] = {};

  for (int k0 = 0; k0 < 1024; k0 += 64) {
    load_lds16(gAh + k0, lAh);
    load_lds16(gAh + k0 + 8 * 1024, lAh + 8 * 64);
    load_lds16(gBh + k0, lBh);
    load_lds16(gBh + k0 + 8 * 1024, lBh + 8 * 64);
    __syncthreads();

    short8 ah[2][2], bh[2][2];
#pragma unroll
    for (int mi = 0; mi < 2; ++mi) {
      int row = wm + mi * 16 + fr;
#pragma unroll
      for (int ks = 0; ks < 2; ++ks)
        ah[mi][ks] = *(const short8*)&AsH[row * 64 +
                         ((ks * 32 + kg * 8) ^ ((fr & 7) << 3))];
    }
#pragma unroll
    for (int ni = 0; ni < 2; ++ni) {
      int row = wn + ni * 16 + fr;
#pragma unroll
      for (int ks = 0; ks < 2; ++ks)
        bh[ni][ks] = *(const short8*)&BsH[row * 64 +
                         ((ks * 32 + kg * 8) ^ ((fr & 7) << 3))];
    }
#pragma unroll
    for (int ks = 0; ks < 2; ++ks)
#pragma unroll
      for (int mi = 0; mi < 2; ++mi)
#pragma unroll
        for (int ni = 0; ni < 2; ++ni)
          acc[mi][ni] = mfma16(ah[mi][ks], bh[ni][ks], acc[mi][ni]);
    __syncthreads();
  }

#pragma unroll
  for (int mi = 0; mi < 2; ++mi)
#pragma unroll
    for (int ni = 0; ni < 2; ++ni) {
      int gnc = n0 + wn + ni * 16 + fr;
      float bv = bgp[gnc];
#pragma unroll
      for (int r = 0; r < 4; ++r) {
        int gm = m0 + wm + mi * 16 + kg * 4 + r;
        long idx = (long)gm * D_ + gnc;
        float g = 1.f / (1.f + expf(-(acc[mi][ni][r] + bv)));
        fused[idx] = f2bf(g * ctxf[idx] + (1.f - g) * msf[idx]);
      }
    }
}

// ---------------------------------------------------------------------------
// Logits GEMM: 256x128 tile, BK=32, double-buffered, counted vmcnt, nt stores.
// ---------------------------------------------------------------------------
__global__ __launch_bounds__(512, 4) void logits_gemm_bk32_k(
    const u16* __restrict__ A, const u16* __restrict__ Bt,
    const float* __restrict__ bias, float* __restrict__ C)
{
  __shared__ u16 As[2][256 * 32];
  __shared__ u16 Bs[2][128 * 32];

  const int id = blockIdx.x;
  const int swz = (id & 7) * 250 + (id >> 3);
  const int m0 = (swz & 7) * 256;
  const int n0 = (swz >> 3) * 128;

  const int tid = threadIdx.x;
  const int lane = tid & 63;
  const int wid = tid >> 6;
  const int wr = wid >> 1;
  const int wc = wid & 1;
  const int fr = lane & 15, kg = lane >> 4;
  const int srow = lane >> 2;
  const int schunk = (lane & 3) ^ (srow & 3);

  f32x4 acc[4][4] = {};
  short8 a[4], b[4];

  auto stage = [&](int kt) {
    const int buf = kt & 1;
    const long kc = (long)kt * 32 + schunk * 8;
    load_lds16(A + (long)(m0 + wid * 16 + srow) * D_ + kc,
               &As[buf][(wid * 16) * 32]);
    load_lds16(A + (long)(m0 + 128 + wid * 16 + srow) * D_ + kc,
               &As[buf][(128 + wid * 16) * 32]);
    load_lds16(Bt + (long)(n0 + wid * 16 + srow) * D_ + kc,
               &Bs[buf][(wid * 16) * 32]);
  };
  auto readfrags = [&](int buf) {
#pragma unroll
    for (int mi = 0; mi < 4; ++mi) {
      int row = wr * 64 + mi * 16 + fr;
      a[mi] = *(const short8*)&As[buf][row * 32 + ((kg ^ (row & 3)) * 8)];
    }
#pragma unroll
    for (int ni = 0; ni < 4; ++ni) {
      int row = wc * 64 + ni * 16 + fr;
      b[ni] = *(const short8*)&Bs[buf][row * 32 + ((kg ^ (row & 3)) * 8)];
    }
  };

  stage(0);
  stage(1);

  for (int t = 0; t < 16; ++t) {
    __builtin_amdgcn_sched_barrier(0);
    if (t < 15) { asm volatile("s_waitcnt vmcnt(3)" ::: "memory"); }
    else        { asm volatile("s_waitcnt vmcnt(0)" ::: "memory"); }
    __builtin_amdgcn_s_barrier();
    __builtin_amdgcn_sched_barrier(0);

    readfrags(t & 1);
    asm volatile("s_waitcnt lgkmcnt(0)" ::: "memory");
    __builtin_amdgcn_sched_barrier(0);
    __builtin_amdgcn_s_barrier();
    __builtin_amdgcn_sched_barrier(0);

    if (t + 2 < 16) stage(t + 2);

    __builtin_amdgcn_sched_barrier(0);
    __builtin_amdgcn_s_setprio(1);
#pragma unroll
    for (int mi = 0; mi < 4; ++mi)
#pragma unroll
      for (int ni = 0; ni < 4; ++ni)
        acc[mi][ni] = mfma16(a[mi], b[ni], acc[mi][ni]);
    __builtin_amdgcn_s_setprio(0);
    __builtin_amdgcn_sched_barrier(0);
  }

#pragma unroll
  for (int ni = 0; ni < 4; ++ni) {
    int gnc = n0 + wc * 64 + ni * 16 + fr;
    float bv = bias[gnc];
#pragma unroll
    for (int mi = 0; mi < 4; ++mi)
#pragma unroll
      for (int r = 0; r < 4; ++r) {
        int gm = m0 + wr * 64 + mi * 16 + kg * 4 + r;
        __builtin_nontemporal_store(acc[mi][ni][r] + bv, &C[(long)gm * V_ + gnc]);
      }
  }
}

// ---------------------------------------------------------------------------
// ALL weight preprocessing in ONE launch.
// ---------------------------------------------------------------------------
__global__ __launch_bounds__(256) void prep_weights_k(
    const float* __restrict__ Wq, const float* __restrict__ Wk,
    const float* __restrict__ Wv, const float* __restrict__ Wo,
    const float* __restrict__ Wgc, const float* __restrict__ Wgm,
    const float* __restrict__ Wd,
    u16* __restrict__ wqkvTh, u16* __restrict__ wqkvTl,
    u16* __restrict__ woTh, u16* __restrict__ woTl,
    u16* __restrict__ wgT, u16* __restrict__ wdT)
{
  const int bid = blockIdx.x;
  const float* W; u16 *oh, *ol = nullptr;
  int ldw, ldo, koff = 0, nb, kb;
  bool LO = false;
  if (bid < 384) {
    const int w = bid >> 6, tt = bid & 63;
    nb = tt & 7; kb = tt >> 3;
    ldw = 512; ldo = 512;
    switch (w) {
      case 0: W = Wq;  oh = wqkvTh;               ol = wqkvTl;               LO = true; break;
      case 1: W = Wk;  oh = wqkvTh + 512 * 512;   ol = wqkvTl + 512 * 512;   LO = true; break;
      case 2: W = Wv;  oh = wqkvTh + 2 * 512 * 512; ol = wqkvTl + 2 * 512 * 512; LO = true; break;
      case 3: W = Wo;  oh = woTh;                 ol = woTl;                 LO = true; break;
      case 4: W = Wgc; oh = wgT; ldo = 1024; break;
      default: W = Wgm; oh = wgT; ldo = 1024; koff = 512; break;
    }
  } else {
    const int tt = bid - 384;
    nb = tt % 500; kb = tt / 500;
    W = Wd; ldw = V_; ldo = 512; oh = wdT;
  }
  const int n0 = nb * 64, k0 = kb * 64;
  const int tid = threadIdx.x;
  __shared__ float t[64][65];
  {
    const int kk = tid >> 4;
    const int c4 = (tid & 15) * 4;
#pragma unroll
    for (int i = 0; i < 4; ++i) {
      f32x4 v = *(const f32x4*)(W + (long)(k0 + kk + i * 16) * ldw + n0 + c4);
      t[kk + i * 16][c4] = v[0];
      t[kk + i * 16][c4 + 1] = v[1];
      t[kk + i * 16][c4 + 2] = v[2];
      t[kk + i * 16][c4 + 3] = v[3];
    }
  }
  __syncthreads();
  {
    const int chunk = tid & 7;
    const int nn = tid >> 3;
#pragma unroll
    for (int j = 0; j < 2; ++j) {
      int n = nn + j * 32;
      u16 hbuf[8], lbuf[8];
#pragma unroll
      for (int e = 0; e < 8; ++e) {
        float fv = t[chunk * 8 + e][n];
        u16 h = f2bf(fv);
        hbuf[e] = h;
        lbuf[e] = f2bf(fv - bf2f(h));
      }
      long ob = (long)(n0 + n) * ldo + koff + k0 + chunk * 8;
      *(short8*)(oh + ob) = *(short8*)hbuf;
      if (LO) *(short8*)(ol + ob) = *(short8*)lbuf;
    }
  }
}

// v slice of qkv (split pair) -> vT (z, 64, 512) split pair
__global__ __launch_bounds__(256) void v_transpose_k(
    const u16* __restrict__ qh, const u16* __restrict__ ql,
    u16* __restrict__ vTh, u16* __restrict__ vTl)
{
  __shared__ u16 th[64][68];
  __shared__ u16 tl[64][68];
  const int z = blockIdx.y;            // b*8+h
  const int b = z >> 3, h = z & 7;
  const int s0 = blockIdx.x * 64;
  const long ibase = ((long)(b * 512 + s0)) * 1536 + 1024 + h * 64;
  const int tid = threadIdx.x;
  {
    const int sr = tid >> 2;
    const int c8 = (tid & 3) * 16;
    const long src = ibase + (long)sr * 1536 + c8;
    *(short8*)&th[sr][c8]     = *(const short8*)(qh + src);
    *(short8*)&th[sr][c8 + 8] = *(const short8*)(qh + src + 8);
    *(short8*)&tl[sr][c8]     = *(const short8*)(ql + src);
    *(short8*)&tl[sr][c8 + 8] = *(const short8*)(ql + src + 8);
  }
  __syncthreads();
  {
    const int dr = tid >> 2;
    const int s8 = (tid & 3) * 16;
    u16 oh[16], ol[16];
#pragma unroll
    for (int j = 0; j < 16; ++j) { oh[j] = th[s8 + j][dr]; ol[j] = tl[s8 + j][dr]; }
    long ob = (long)z * 64 * 512 + (long)dr * 512 + s0 + s8;
    *(short8*)(vTh + ob)     = *(short8*)&oh[0];
    *(short8*)(vTh + ob + 8) = *(short8*)&oh[8];
    *(short8*)(vTl + ob)     = *(short8*)&ol[0];
    *(short8*)(vTl + ob + 8) = *(short8*)&ol[8];
  }
}

// ---------------------------------------------------------------------------
__global__ __launch_bounds__(128) void embed_k(const int* __restrict__ ids,
                                               const float* __restrict__ emb,
                                               float* __restrict__ x,
                                               u16* __restrict__ xh,
                                               u16* __restrict__ xl) {
  const int t = blockIdx.x;
  const long id = ids[t];
  const int c = threadIdx.x * 4;
  f32x4 v = *(const f32x4*)(emb + id * (long)D_ + c);
  *(f32x4*)(x + (long)t * D_ + c) = v;
  u16 hh[4], ll[4];
#pragma unroll
  for (int j = 0; j < 4; ++j) {
    u16 h = f2bf(v[j]);
    hh[j] = h;
    ll[j] = f2bf(v[j] - bf2f(h));
  }
  *(unsigned long long*)(xh + (long)t * D_ + c) = *(unsigned long long*)hh;
  *(unsigned long long*)(xl + (long)t * D_ + c) = *(unsigned long long*)ll;
}

// ---------------------------------------------------------------------------
// FUSED: LayerNorm(x+proj) -> {ctxf, catA[:,0:512]} then router argmax,
// top-4 over 128 keys, memory stream -> {msf, catA[:,512:1024]}.
// ---------------------------------------------------------------------------
__global__ __launch_bounds__(128) void ln_route_k(
    const float* __restrict__ x, const float* __restrict__ proj,
    const float* __restrict__ g, const float* __restrict__ b,
    const float* __restrict__ Wr, const float* __restrict__ keys,
    const float* __restrict__ valsm,
    float* __restrict__ ctxf, u16* __restrict__ catA, float* __restrict__ msf)
{
  const int t = blockIdx.x;
  const int tid = threadIdx.x;
  __shared__ float sctx[D_];
  __shared__ float red2[4];
  __shared__ float spart[CAP_];
  __shared__ float sred2[2][64];
  __shared__ int s_route;
  __shared__ int sidx[4];
  __shared__ float sw[4];

  const int c = tid * 4;
  f32x4 xv = *(const f32x4*)(x + (long)t * D_ + c);
  f32x4 pv = *(const f32x4*)(proj + (long)t * D_ + c);
  float v0 = xv[0] + pv[0], v1 = xv[1] + pv[1];
  float v2 = xv[2] + pv[2], v3 = xv[3] + pv[3];
  float s = v0 + v1 + v2 + v3;
  float q = v0 * v0 + v1 * v1 + v2 * v2 + v3 * v3;
#pragma unroll
  for (int off = 32; off; off >>= 1) { s += __shfl_xor(s, off); q += __shfl_xor(q, off); }
  const int wave = tid >> 6, lane = tid & 63;
  if (lane == 0) { red2[wave] = s; red2[2 + wave] = q; }
  __syncthreads();
  s = red2[0] + red2[1];
  q = red2[2] + red2[3];
  float mu = s * (1.f / 512.f);
  float var = q * (1.f / 512.f) - mu * mu;
  float rs = rsqrtf(var + 1e-5f);
  f32x4 gv = *(const f32x4*)(g + c);
  f32x4 bv = *(const f32x4*)(b + c);
  f32x4 of;
  of[0] = (v0 - mu) * rs * gv[0] + bv[0];
  of[1] = (v1 - mu) * rs * gv[1] + bv[1];
  of[2] = (v2 - mu) * rs * gv[2] + bv[2];
  of[3] = (v3 - mu) * rs * gv[3] + bv[3];
  *(f32x4*)(ctxf + (long)t * D_ + c) = of;
  ((f32x4*)sctx)[tid] = of;
  {
    u16 hh[4];
#pragma unroll
    for (int j = 0; j < 4; ++j) hh[j] = f2bf(of[j]);
    *(unsigned long long*)(catA + (long)t * 1024 + c) = *(unsigned long long*)hh;
  }
  __syncthreads();

  {
    const int cc = tid & 63, half = tid >> 6;
    float accr = 0.f;
    const float* cp = sctx + half * 256;
    const float* wp = Wr + (long)(half * 256) * NSHARD_ + cc;
    for (int d = 0; d < 256; ++d) accr += cp[d] * wp[(long)d * NSHARD_];
    sred2[half][cc] = accr;
  }
  __syncthreads();
  if (tid < 64) {
    float v = sred2[0][tid] + sred2[1][tid];
    int idx = tid;
#pragma unroll
    for (int off = 32; off; off >>= 1) {
      float ov = __shfl_xor(v, off);
      int oi = __shfl_xor(idx, off);
      if (ov > v || (ov == v && oi < idx)) { v = ov; idx = oi; }
    }
    if (tid == 0) s_route = idx;
  }
  __syncthreads();
  const int route = s_route;

  {
    const float* krow = keys + ((long)route * CAP_ + tid) * D_;
    float sc = 0.f;
    for (int d0 = 0; d0 < D_; d0 += 4) {
      f32x4 kv = *(const f32x4*)(krow + d0);
      sc += sctx[d0] * kv[0] + sctx[d0 + 1] * kv[1] +
            sctx[d0 + 2] * kv[2] + sctx[d0 + 3] * kv[3];
    }
    spart[tid] = sc;
  }
  __syncthreads();

  for (int rep = 0; rep < 4; ++rep) {
    if (tid < 64) {
      float v1r = spart[tid]; int i1 = tid;
      float v2r = spart[tid + 64]; int i2 = tid + 64;
      float v; int idx;
      if (v2r > v1r) { v = v2r; idx = i2; } else { v = v1r; idx = i1; }
#pragma unroll
      for (int off = 32; off; off >>= 1) {
        float ov = __shfl_xor(v, off);
        int oi = __shfl_xor(idx, off);
        if (ov > v || (ov == v && oi < idx)) { v = ov; idx = oi; }
      }
      if (tid == 0) { sidx[rep] = idx; sw[rep] = v; spart[idx] = -3.4e38f; }
    }
    __syncthreads();
  }

  float w0 = sw[0], w1 = sw[1], w2 = sw[2], w3 = sw[3];
  float mx = fmaxf(fmaxf(w0, w1), fmaxf(w2, w3));
  float e0 = expf(w0 - mx), e1 = expf(w1 - mx), e2 = expf(w2 - mx), e3 = expf(w3 - mx);
  float inv = 1.f / (e0 + e1 + e2 + e3);
  float wk[4] = {e0 * inv, e1 * inv, e2 * inv, e3 * inv};

  float a0 = 0, a1 = 0, a2 = 0, a3 = 0;
#pragma unroll
  for (int k = 0; k < 4; ++k) {
    const float* vr = valsm + ((long)route * CAP_ + sidx[k]) * D_ + c;
    f32x4 vv = *(const f32x4*)vr;
    float w = wk[k];
    a0 += w * vv[0]; a1 += w * vv[1]; a2 += w * vv[2]; a3 += w * vv[3];
  }
  f32x4 om; om[0] = a0; om[1] = a1; om[2] = a2; om[3] = a3;
  *(f32x4*)(msf + (long)t * D_ + c) = om;
  u16 ohh[4];
  ohh[0] = f2bf(a0); ohh[1] = f2bf(a1); ohh[2] = f2bf(a2); ohh[3] = f2bf(a3);
  *(unsigned long long*)(catA + (long)t * 1024 + 512 + c) =
      *(unsigned long long*)ohh;
}

// ---------------------------------------------------------------------------
extern "C" void kernel_launch(void* const* d_in, const int* in_sizes, int n_in,
                              void* d_out, int out_size, void* d_ws, size_t ws_size,
                              hipStream_t stream) {
  const int*   ids  = (const int*)d_in[0];
  const float* emb  = (const float*)d_in[1];
  const float* Wq   = (const float*)d_in[2];
  const float* Wk   = (const float*)d_in[3];
  const float* Wv   = (const float*)d_in[4];
  const float* Wo   = (const float*)d_in[5];
  const float* ln_g = (const float*)d_in[6];
  const float* ln_b = (const float*)d_in[7];
  const float* Wr   = (const float*)d_in[8];
  const float* mk   = (const float*)d_in[9];
  const float* mv   = (const float*)d_in[10];
  const float* Wgc  = (const float*)d_in[11];
  const float* Wgm  = (const float*)d_in[12];
  const float* bg   = (const float*)d_in[13];
  const float* Wd   = (const float*)d_in[14];
  const float* bd   = (const float*)d_in[15];
  float* out = (float*)d_out;

  char* ws = (char*)d_ws;
  size_t off = 0;
  auto alloc = [&](size_t bytes) -> void* {
    void* p = ws + off;
    off += (bytes + 255) & ~(size_t)255;
    return p;
  };
  float* x      = (float*)alloc((size_t)TOK_ * D_ * 4);
  u16*   xh     = (u16*)  alloc((size_t)TOK_ * D_ * 2);
  u16*   xl     = (u16*)  alloc((size_t)TOK_ * D_ * 2);
  u16*   wqkvTh = (u16*)  alloc((size_t)3 * D_ * D_ * 2);
  u16*   wqkvTl = (u16*)  alloc((size_t)3 * D_ * D_ * 2);
  u16*   woTh   = (u16*)  alloc((size_t)D_ * D_ * 2);
  u16*   woTl   = (u16*)  alloc((size_t)D_ * D_ * 2);
  u16*   wgT    = (u16*)  alloc((size_t)D_ * 1024 * 2);
  u16*   wdT    = (u16*)  alloc((size_t)D_ * V_ * 2);
  u16*   qkvh   = (u16*)  alloc((size_t)TOK_ * 3 * D_ * 2);
  u16*   qkvl   = (u16*)  alloc((size_t)TOK_ * 3 * D_ * 2);
  u16*   vTh    = (u16*)  alloc((size_t)B_ * H_ * HD_ * S_ * 2);
  u16*   vTl    = (u16*)  alloc((size_t)B_ * H_ * HD_ * S_ * 2);
  u16*   oh     = (u16*)  alloc((size_t)TOK_ * D_ * 2);
  u16*   ol     = (u16*)  alloc((size_t)TOK_ * D_ * 2);
  float* proj   = (float*)alloc((size_t)TOK_ * D_ * 4);
  float* ctxf   = (float*)alloc((size_t)TOK_ * D_ * 4);
  u16*   catA   = (u16*)  alloc((size_t)TOK_ * 1024 * 2);
  float* msf    = (float*)alloc((size_t)TOK_ * D_ * 4);
  u16*   fused  = (u16*)  alloc((size_t)TOK_ * D_ * 2);

  // 0) ALL weight preprocessing in one launch
  prep_weights_k<<<4384, 256, 0, stream>>>(
      Wq, Wk, Wv, Wo, Wgc, Wgm, Wd,
      wqkvTh, wqkvTl, woTh, woTl, wgT, wdT);

  // 1) embed gather + split
  embed_k<<<TOK_, 128, 0, stream>>>(ids, emb, x, xh, xl);

  // 2) qkv = x @ [Wq|Wk|Wv]  (split pair out)
  {
    dim3 g(1536 / 64, TOK_ / 64, 1);
    gemm_bt<3, 1><<<g, 256, 0, stream>>>(
        xh, xl, D_, wqkvTh, wqkvTl, D_, qkvh, qkvl, 1536, D_);
  }

  // 3) vT per-head transpose
  {
    dim3 g(S_ / 64, B_ * H_, 1);
    v_transpose_k<<<g, 256, 0, stream>>>(qkvh, qkvl, vTh, vTl);
  }

  // 4) FUSED flash attention -> oh/ol split pair
  {
    dim3 g(S_ / 64, B_ * H_, 1);
    attn_k<<<g, 256, 0, stream>>>(qkvh, qkvl, vTh, vTl, oh, ol);
  }

  // 5) proj = o @ Wo
  {
    dim3 g(D_ / 64, TOK_ / 64, 1);
    gemm_bt<3, 0><<<g, 256, 0, stream>>>(
        oh, ol, D_, woTh, woTl, D_, proj, nullptr, D_, D_);
  }

  // 6) FUSED: LN + routing + memory stream
  ln_route_k<<<TOK_, 128, 0, stream>>>(
      x, proj, ln_g, ln_b, Wr, mk, mv, ctxf, catA, msf);

  // 7) FUSED: gate GEMM (K=1024) + sigmoid-mix epilogue -> fused bf16
  {
    dim3 g(D_ / 64, TOK_ / 64, 1);
    gate_gemm_k<<<g, 256, 0, stream>>>(catA, wgT, bg, ctxf, msf, fused);
  }

  // 8) logits = fused @ wdT^T + bd
  logits_gemm_bk32_k<<<2000, 512, 0, stream>>>(fused, wdT, bd, out);
}

// Round 12
// 289.686 us; speedup vs baseline: 1.0590x; 1.0590x over previous
//
#include <hip/hip_runtime.h>

typedef unsigned short u16;
typedef float f32x4 __attribute__((ext_vector_type(4)));
typedef short short8 __attribute__((ext_vector_type(8)));
typedef __bf16 bf16x8 __attribute__((ext_vector_type(8)));
typedef unsigned long long ull;

#define B_  4
#define S_  512
#define D_  512
#define H_  8
#define HD_ 64
#define V_  32000
#define NSHARD_ 64
#define CAP_ 128
#define TOK_ (B_ * S_)

__device__ __forceinline__ float bf2f(u16 u) { return __uint_as_float(((unsigned)u) << 16); }
__device__ __forceinline__ u16 f2bf(float f) {
  unsigned u = __float_as_uint(f);
  u += 0x7FFFu + ((u >> 16) & 1u);
  return (u16)(u >> 16);
}

__device__ __forceinline__ f32x4 mfma16(short8 a, short8 b, f32x4 c) {
  return __builtin_amdgcn_mfma_f32_16x16x32_bf16(
      __builtin_bit_cast(bf16x8, a), __builtin_bit_cast(bf16x8, b), c, 0, 0, 0);
}

__device__ __forceinline__ void load_lds16(const void* g, void* l) {
  __builtin_amdgcn_global_load_lds(
      (const __attribute__((address_space(1))) void*)g,
      (__attribute__((address_space(3))) void*)l, 16, 0, 0);
}

// ---------------------------------------------------------------------------
// Unified GEMM: all operands bf16, (rows, K) row-major ("BT" layout).
// NS: 1 = hi only; 3 = hi+lo pairs (3 MFMAs, ~f32 accuracy).
// OM: 0 = f32 out; 1 = split bf16 pair out.  CKLIM: causal K-limit.
// ---------------------------------------------------------------------------
template<int NS, bool ACC, int OM, bool CKLIM>
__global__ __launch_bounds__(256) void gemm_bt(
    const u16* __restrict__ Ah, const u16* __restrict__ Al, int ldA, long sA1, long sA2,
    const u16* __restrict__ Bh, const u16* __restrict__ Bl, int ldB, long sB1, long sB2,
    void* __restrict__ C0, void* __restrict__ C1, int ldC, long sC1, long sC2,
    int K, int z2n, float alpha)
{
  __shared__ u16 AsH[64 * 64];
  __shared__ u16 BsH[64 * 64];
  __shared__ u16 AsL[(NS == 3) ? 64 * 64 : 8];
  __shared__ u16 BsL[(NS == 3) ? 64 * 64 : 8];

  const int n0 = blockIdx.x * 64;
  const int m0 = blockIdx.y * 64;

  const int z = blockIdx.z;
  const int z1 = z / z2n, z2 = z - z1 * z2n;
  const long baseA = (long)z1 * sA1 + (long)z2 * sA2;
  const long baseB = (long)z1 * sB1 + (long)z2 * sB2;
  const long baseC = (long)z1 * sC1 + (long)z2 * sC2;

  const int tid = threadIdx.x;
  const int lane = tid & 63;
  const int w = tid >> 6;
  const int wm = (w >> 1) * 32, wn = (w & 1) * 32;
  const int fr = lane & 15, kg = lane >> 4;

  const int srow = lane >> 3;
  const int schunk = (lane & 7) ^ srow;

  const u16* gAh = Ah + baseA + (long)(m0 + w * 16 + srow) * ldA + schunk * 8;
  const u16* gBh = Bh + baseB + (long)(n0 + w * 16 + srow) * ldB + schunk * 8;
  const u16* gAl = (NS == 3) ? (Al + baseA + (long)(m0 + w * 16 + srow) * ldA + schunk * 8) : nullptr;
  const u16* gBl = (NS == 3) ? (Bl + baseB + (long)(n0 + w * 16 + srow) * ldB + schunk * 8) : nullptr;
  u16* lAh = &AsH[(w * 16) * 64];
  u16* lBh = &BsH[(w * 16) * 64];
  u16* lAl = &AsL[(NS == 3) ? (w * 16) * 64 : 0];
  u16* lBl = &BsL[(NS == 3) ? (w * 16) * 64 : 0];

  const int kmax = CKLIM ? (m0 + 64) : K;

  f32x4 acc[2][2] = {};

  for (int k0 = 0; k0 < kmax; k0 += 64) {
    load_lds16(gAh + k0, lAh);
    load_lds16(gAh + k0 + 8 * ldA, lAh + 8 * 64);
    load_lds16(gBh + k0, lBh);
    load_lds16(gBh + k0 + 8 * ldB, lBh + 8 * 64);
    if (NS == 3) {
      load_lds16(gAl + k0, lAl);
      load_lds16(gAl + k0 + 8 * ldA, lAl + 8 * 64);
      load_lds16(gBl + k0, lBl);
      load_lds16(gBl + k0 + 8 * ldB, lBl + 8 * 64);
    }
    __syncthreads();

    short8 ah[2][2], bh[2][2], al[2][2], bl[2][2];
#pragma unroll
    for (int mi = 0; mi < 2; ++mi) {
      int row = wm + mi * 16 + fr;
#pragma unroll
      for (int ks = 0; ks < 2; ++ks) {
        int idx = row * 64 + ((ks * 32 + kg * 8) ^ ((fr & 7) << 3));
        ah[mi][ks] = *(const short8*)&AsH[idx];
        if (NS == 3) al[mi][ks] = *(const short8*)&AsL[idx];
      }
    }
#pragma unroll
    for (int ni = 0; ni < 2; ++ni) {
      int row = wn + ni * 16 + fr;
#pragma unroll
      for (int ks = 0; ks < 2; ++ks) {
        int idx = row * 64 + ((ks * 32 + kg * 8) ^ ((fr & 7) << 3));
        bh[ni][ks] = *(const short8*)&BsH[idx];
        if (NS == 3) bl[ni][ks] = *(const short8*)&BsL[idx];
      }
    }
#pragma unroll
    for (int ks = 0; ks < 2; ++ks)
#pragma unroll
      for (int mi = 0; mi < 2; ++mi)
#pragma unroll
        for (int ni = 0; ni < 2; ++ni) {
          acc[mi][ni] = mfma16(ah[mi][ks], bh[ni][ks], acc[mi][ni]);
          if (NS == 3) {
            acc[mi][ni] = mfma16(ah[mi][ks], bl[ni][ks], acc[mi][ni]);
            acc[mi][ni] = mfma16(al[mi][ks], bh[ni][ks], acc[mi][ni]);
          }
        }
    __syncthreads();
  }

#pragma unroll
  for (int mi = 0; mi < 2; ++mi)
#pragma unroll
    for (int ni = 0; ni < 2; ++ni) {
      int gnc = n0 + wn + ni * 16 + fr;
#pragma unroll
      for (int r = 0; r < 4; ++r) {
        int gm = m0 + wm + mi * 16 + kg * 4 + r;
        float v = acc[mi][ni][r] * alpha;
        long idx = baseC + (long)gm * ldC + gnc;
        if (OM == 0) {
          float* C = (float*)C0;
          C[idx] = ACC ? (C[idx] + v) : v;
        } else {
          u16 h = f2bf(v);
          ((u16*)C0)[idx] = h;
          ((u16*)C1)[idx] = f2bf(v - bf2f(h));
        }
      }
    }
}

// ---------------------------------------------------------------------------
// MEGA: z<32 -> QK^T direct-register tile (K=64, causal block-skip);
//       z>=32 -> one 64x64 Wd transpose/convert tile (result needed only by
//       the logits GEMM, 5 dispatches later -> ordering trivially safe).
// ---------------------------------------------------------------------------
__global__ __launch_bounds__(256) void qkt_wd_k(
    const u16* __restrict__ qkvh, const u16* __restrict__ qkvl,
    float* __restrict__ att,
    const float* __restrict__ Wd, u16* __restrict__ wdT)
{
  __shared__ float t[64][65];
  const int z = blockIdx.z;
  const int tid = threadIdx.x;

  if (z >= 32) {
    const int tt = (z - 32) * 64 + blockIdx.y * 8 + blockIdx.x;
    if (tt >= 4000) return;
    const int nb = tt % 500, kb = tt / 500;
    const int n0 = nb * 64, k0 = kb * 64;
    {
      const int kk = tid >> 4;
      const int c4 = (tid & 15) * 4;
#pragma unroll
      for (int i = 0; i < 4; ++i) {
        f32x4 v = *(const f32x4*)(Wd + (long)(k0 + kk + i * 16) * V_ + n0 + c4);
        t[kk + i * 16][c4] = v[0];
        t[kk + i * 16][c4 + 1] = v[1];
        t[kk + i * 16][c4 + 2] = v[2];
        t[kk + i * 16][c4 + 3] = v[3];
      }
    }
    __syncthreads();
    {
      const int chunk = tid & 7;
      const int nn = tid >> 3;
#pragma unroll
      for (int j = 0; j < 2; ++j) {
        int n = nn + j * 32;
        u16 hbuf[8];
#pragma unroll
        for (int e = 0; e < 8; ++e) hbuf[e] = f2bf(t[chunk * 8 + e][n]);
        *(short8*)(wdT + (long)(n0 + n) * 512 + k0 + chunk * 8) = *(short8*)hbuf;
      }
    }
    return;
  }

  const int n0 = blockIdx.x * 64;
  const int m0 = blockIdx.y * 64;
  if (n0 > m0 + 63) return;
  const int b = z >> 3, h = z & 7;
  const long qbase = (long)b * 512 * 1536 + h * 64;
  const long kbase = qbase + 512;
  const long cbase = (long)z * 512 * 512;

  const int lane = tid & 63;
  const int w = tid >> 6;
  const int wm = (w >> 1) * 32, wn = (w & 1) * 32;
  const int fr = lane & 15, kg = lane >> 4;

  short8 ah[2][2], al[2][2], bh[2][2], bl[2][2];
#pragma unroll
  for (int mi = 0; mi < 2; ++mi)
#pragma unroll
    for (int ks = 0; ks < 2; ++ks) {
      long ra = qbase + (long)(m0 + wm + mi * 16 + fr) * 1536 + ks * 32 + kg * 8;
      ah[mi][ks] = *(const short8*)(qkvh + ra);
      al[mi][ks] = *(const short8*)(qkvl + ra);
    }
#pragma unroll
  for (int ni = 0; ni < 2; ++ni)
#pragma unroll
    for (int ks = 0; ks < 2; ++ks) {
      long rb = kbase + (long)(n0 + wn + ni * 16 + fr) * 1536 + ks * 32 + kg * 8;
      bh[ni][ks] = *(const short8*)(qkvh + rb);
      bl[ni][ks] = *(const short8*)(qkvl + rb);
    }

  f32x4 acc[2][2] = {};
#pragma unroll
  for (int ks = 0; ks < 2; ++ks)
#pragma unroll
    for (int mi = 0; mi < 2; ++mi)
#pragma unroll
      for (int ni = 0; ni < 2; ++ni) {
        acc[mi][ni] = mfma16(ah[mi][ks], bh[ni][ks], acc[mi][ni]);
        acc[mi][ni] = mfma16(ah[mi][ks], bl[ni][ks], acc[mi][ni]);
        acc[mi][ni] = mfma16(al[mi][ks], bh[ni][ks], acc[mi][ni]);
      }

#pragma unroll
  for (int mi = 0; mi < 2; ++mi)
#pragma unroll
    for (int ni = 0; ni < 2; ++ni) {
      int gnc = n0 + wn + ni * 16 + fr;
#pragma unroll
      for (int r = 0; r < 4; ++r) {
        int gm = m0 + wm + mi * 16 + kg * 4 + r;
        att[cbase + (long)gm * 512 + gnc] = acc[mi][ni][r] * 0.125f;
      }
    }
}

// ---------------------------------------------------------------------------
// Gate GEMM with fused sigmoid-mix epilogue.
// ---------------------------------------------------------------------------
__global__ __launch_bounds__(256) void gate_gemm_k(
    const u16* __restrict__ Ah, const u16* __restrict__ Bh,
    const float* __restrict__ bgp, const float* __restrict__ ctxf,
    const float* __restrict__ msf, u16* __restrict__ fused)
{
  __shared__ u16 AsH[64 * 64];
  __shared__ u16 BsH[64 * 64];

  const int n0 = blockIdx.x * 64;
  const int m0 = blockIdx.y * 64;
  const int tid = threadIdx.x;
  const int lane = tid & 63;
  const int w = tid >> 6;
  const int wm = (w >> 1) * 32, wn = (w & 1) * 32;
  const int fr = lane & 15, kg = lane >> 4;
  const int srow = lane >> 3;
  const int schunk = (lane & 7) ^ srow;

  const u16* gAh = Ah + (long)(m0 + w * 16 + srow) * 1024 + schunk * 8;
  const u16* gBh = Bh + (long)(n0 + w * 16 + srow) * 1024 + schunk * 8;
  u16* lAh = &AsH[(w * 16) * 64];
  u16* lBh = &BsH[(w * 16) * 64];

  f32x4 acc[2][2] = {};

  for (int k0 = 0; k0 < 1024; k0 += 64) {
    load_lds16(gAh + k0, lAh);
    load_lds16(gAh + k0 + 8 * 1024, lAh + 8 * 64);
    load_lds16(gBh + k0, lBh);
    load_lds16(gBh + k0 + 8 * 1024, lBh + 8 * 64);
    __syncthreads();

    short8 ah[2][2], bh[2][2];
#pragma unroll
    for (int mi = 0; mi < 2; ++mi) {
      int row = wm + mi * 16 + fr;
#pragma unroll
      for (int ks = 0; ks < 2; ++ks)
        ah[mi][ks] = *(const short8*)&AsH[row * 64 +
                         ((ks * 32 + kg * 8) ^ ((fr & 7) << 3))];
    }
#pragma unroll
    for (int ni = 0; ni < 2; ++ni) {
      int row = wn + ni * 16 + fr;
#pragma unroll
      for (int ks = 0; ks < 2; ++ks)
        bh[ni][ks] = *(const short8*)&BsH[row * 64 +
                         ((ks * 32 + kg * 8) ^ ((fr & 7) << 3))];
    }
#pragma unroll
    for (int ks = 0; ks < 2; ++ks)
#pragma unroll
      for (int mi = 0; mi < 2; ++mi)
#pragma unroll
        for (int ni = 0; ni < 2; ++ni)
          acc[mi][ni] = mfma16(ah[mi][ks], bh[ni][ks], acc[mi][ni]);
    __syncthreads();
  }

#pragma unroll
  for (int mi = 0; mi < 2; ++mi)
#pragma unroll
    for (int ni = 0; ni < 2; ++ni) {
      int gnc = n0 + wn + ni * 16 + fr;
      float bv = bgp[gnc];
#pragma unroll
      for (int r = 0; r < 4; ++r) {
        int gm = m0 + wm + mi * 16 + kg * 4 + r;
        long idx = (long)gm * D_ + gnc;
        float g = 1.f / (1.f + expf(-(acc[mi][ni][r] + bv)));
        fused[idx] = f2bf(g * ctxf[idx] + (1.f - g) * msf[idx]);
      }
    }
}

// ---------------------------------------------------------------------------
// Logits GEMM: 256x128 tile, BK=32, double-buffered, counted vmcnt, nt stores.
// ---------------------------------------------------------------------------
__global__ __launch_bounds__(512, 4) void logits_gemm_bk32_k(
    const u16* __restrict__ A, const u16* __restrict__ Bt,
    const float* __restrict__ bias, float* __restrict__ C)
{
  __shared__ u16 As[2][256 * 32];
  __shared__ u16 Bs[2][128 * 32];

  const int id = blockIdx.x;
  const int swz = (id & 7) * 250 + (id >> 3);
  const int m0 = (swz & 7) * 256;
  const int n0 = (swz >> 3) * 128;

  const int tid = threadIdx.x;
  const int lane = tid & 63;
  const int wid = tid >> 6;
  const int wr = wid >> 1;
  const int wc = wid & 1;
  const int fr = lane & 15, kg = lane >> 4;
  const int srow = lane >> 2;
  const int schunk = (lane & 3) ^ (srow & 3);

  f32x4 acc[4][4] = {};
  short8 a[4], b[4];

  auto stage = [&](int kt) {
    const int buf = kt & 1;
    const long kc = (long)kt * 32 + schunk * 8;
    load_lds16(A + (long)(m0 + wid * 16 + srow) * D_ + kc,
               &As[buf][(wid * 16) * 32]);
    load_lds16(A + (long)(m0 + 128 + wid * 16 + srow) * D_ + kc,
               &As[buf][(128 + wid * 16) * 32]);
    load_lds16(Bt + (long)(n0 + wid * 16 + srow) * D_ + kc,
               &Bs[buf][(wid * 16) * 32]);
  };
  auto readfrags = [&](int buf) {
#pragma unroll
    for (int mi = 0; mi < 4; ++mi) {
      int row = wr * 64 + mi * 16 + fr;
      a[mi] = *(const short8*)&As[buf][row * 32 + ((kg ^ (row & 3)) * 8)];
    }
#pragma unroll
    for (int ni = 0; ni < 4; ++ni) {
      int row = wc * 64 + ni * 16 + fr;
      b[ni] = *(const short8*)&Bs[buf][row * 32 + ((kg ^ (row & 3)) * 8)];
    }
  };

  stage(0);
  stage(1);

  for (int t = 0; t < 16; ++t) {
    __builtin_amdgcn_sched_barrier(0);
    if (t < 15) { asm volatile("s_waitcnt vmcnt(3)" ::: "memory"); }
    else        { asm volatile("s_waitcnt vmcnt(0)" ::: "memory"); }
    __builtin_amdgcn_s_barrier();
    __builtin_amdgcn_sched_barrier(0);

    readfrags(t & 1);
    asm volatile("s_waitcnt lgkmcnt(0)" ::: "memory");
    __builtin_amdgcn_sched_barrier(0);
    __builtin_amdgcn_s_barrier();
    __builtin_amdgcn_sched_barrier(0);

    if (t + 2 < 16) stage(t + 2);

    __builtin_amdgcn_sched_barrier(0);
    __builtin_amdgcn_s_setprio(1);
#pragma unroll
    for (int mi = 0; mi < 4; ++mi)
#pragma unroll
      for (int ni = 0; ni < 4; ++ni)
        acc[mi][ni] = mfma16(a[mi], b[ni], acc[mi][ni]);
    __builtin_amdgcn_s_setprio(0);
    __builtin_amdgcn_sched_barrier(0);
  }

#pragma unroll
  for (int ni = 0; ni < 4; ++ni) {
    int gnc = n0 + wc * 64 + ni * 16 + fr;
    float bv = bias[gnc];
#pragma unroll
    for (int mi = 0; mi < 4; ++mi)
#pragma unroll
      for (int r = 0; r < 4; ++r) {
        int gm = m0 + wr * 64 + mi * 16 + kg * 4 + r;
        __builtin_nontemporal_store(acc[mi][ni][r] + bv, &C[(long)gm * V_ + gnc]);
      }
  }
}

// ---------------------------------------------------------------------------
// Small-weight prep (384 tiles) + embed gather/split (1024 blocks, 2 tok ea).
// ---------------------------------------------------------------------------
__global__ __launch_bounds__(256) void prep_embed_k(
    const float* __restrict__ Wq, const float* __restrict__ Wk,
    const float* __restrict__ Wv, const float* __restrict__ Wo,
    const float* __restrict__ Wgc, const float* __restrict__ Wgm,
    u16* __restrict__ wqkvTh, u16* __restrict__ wqkvTl,
    u16* __restrict__ woTh, u16* __restrict__ woTl,
    u16* __restrict__ wgT,
    const int* __restrict__ ids, const float* __restrict__ emb,
    u16* __restrict__ xh, u16* __restrict__ xl)
{
  const int bid = blockIdx.x;
  const int tid = threadIdx.x;

  if (bid >= 384) {  // embed: two tokens per block
    const int t = (bid - 384) * 2 + (tid >> 7);
    const int c = (tid & 127) * 4;
    const long id = ids[t];
    f32x4 v = *(const f32x4*)(emb + id * (long)D_ + c);
    u16 hh[4], ll[4];
#pragma unroll
    for (int j = 0; j < 4; ++j) {
      u16 h = f2bf(v[j]);
      hh[j] = h;
      ll[j] = f2bf(v[j] - bf2f(h));
    }
    *(ull*)(xh + (long)t * D_ + c) = *(ull*)hh;
    *(ull*)(xl + (long)t * D_ + c) = *(ull*)ll;
    return;
  }

  const float* W; u16 *oh, *ol = nullptr;
  int ldo = 512, koff = 0;
  bool LO = false;
  const int w = bid >> 6, tt = bid & 63;
  const int nb = tt & 7, kb = tt >> 3;
  switch (w) {
    case 0: W = Wq;  oh = wqkvTh;                 ol = wqkvTl;                 LO = true; break;
    case 1: W = Wk;  oh = wqkvTh + 512 * 512;     ol = wqkvTl + 512 * 512;     LO = true; break;
    case 2: W = Wv;  oh = wqkvTh + 2 * 512 * 512; ol = wqkvTl + 2 * 512 * 512; LO = true; break;
    case 3: W = Wo;  oh = woTh;                   ol = woTl;                   LO = true; break;
    case 4: W = Wgc; oh = wgT; ldo = 1024; break;
    default: W = Wgm; oh = wgT; ldo = 1024; koff = 512; break;
  }
  const int n0 = nb * 64, k0 = kb * 64;
  __shared__ float t[64][65];
  {
    const int kk = tid >> 4;
    const int c4 = (tid & 15) * 4;
#pragma unroll
    for (int i = 0; i < 4; ++i) {
      f32x4 v = *(const f32x4*)(W + (long)(k0 + kk + i * 16) * 512 + n0 + c4);
      t[kk + i * 16][c4] = v[0];
      t[kk + i * 16][c4 + 1] = v[1];
      t[kk + i * 16][c4 + 2] = v[2];
      t[kk + i * 16][c4 + 3] = v[3];
    }
  }
  __syncthreads();
  {
    const int chunk = tid & 7;
    const int nn = tid >> 3;
#pragma unroll
    for (int j = 0; j < 2; ++j) {
      int n = nn + j * 32;
      u16 hbuf[8], lbuf[8];
#pragma unroll
      for (int e = 0; e < 8; ++e) {
        float fv = t[chunk * 8 + e][n];
        u16 h = f2bf(fv);
        hbuf[e] = h;
        lbuf[e] = f2bf(fv - bf2f(h));
      }
      long ob = (long)(n0 + n) * ldo + koff + k0 + chunk * 8;
      *(short8*)(oh + ob) = *(short8*)hbuf;
      if (LO) *(short8*)(ol + ob) = *(short8*)lbuf;
    }
  }
}

// v slice of qkv (split pair) -> vT (z, 64, 512) split pair
__global__ __launch_bounds__(256) void v_transpose_k(
    const u16* __restrict__ qh, const u16* __restrict__ ql,
    u16* __restrict__ vTh, u16* __restrict__ vTl)
{
  __shared__ u16 th[64][68];
  __shared__ u16 tl[64][68];
  const int z = blockIdx.y;            // b*8+h
  const int b = z >> 3, h = z & 7;
  const int s0 = blockIdx.x * 64;
  const long ibase = ((long)(b * 512 + s0)) * 1536 + 1024 + h * 64;
  const int tid = threadIdx.x;
  {
    const int sr = tid >> 2;
    const int c8 = (tid & 3) * 16;
    const long src = ibase + (long)sr * 1536 + c8;
    *(short8*)&th[sr][c8]     = *(const short8*)(qh + src);
    *(short8*)&th[sr][c8 + 8] = *(const short8*)(qh + src + 8);
    *(short8*)&tl[sr][c8]     = *(const short8*)(ql + src);
    *(short8*)&tl[sr][c8 + 8] = *(const short8*)(ql + src + 8);
  }
  __syncthreads();
  {
    const int dr = tid >> 2;
    const int s8 = (tid & 3) * 16;
    u16 oh[16], ol[16];
#pragma unroll
    for (int j = 0; j < 16; ++j) { oh[j] = th[s8 + j][dr]; ol[j] = tl[s8 + j][dr]; }
    long ob = (long)z * 64 * 512 + (long)dr * 512 + s0 + s8;
    *(short8*)(vTh + ob)     = *(short8*)&oh[0];
    *(short8*)(vTh + ob + 8) = *(short8*)&oh[8];
    *(short8*)(vTl + ob)     = *(short8*)&ol[0];
    *(short8*)(vTl + ob + 8) = *(short8*)&ol[8];
  }
}

// causal softmax row -> split bf16 pair, vectorized
__global__ __launch_bounds__(64) void softmax_causal_k(
    const float* __restrict__ att, u16* __restrict__ ph, u16* __restrict__ pl) {
  const int row = blockIdx.x;
  const int i = row & 511;
  const long base = (long)row << 9;
  const float* p = att + base;
  const int lane = threadIdx.x;
  const int c0 = lane * 8;
  float v[8];
  float m = -3.4e38f;
  if (c0 <= i) {
    f32x4 a = *(const f32x4*)(p + c0);
    f32x4 b2 = *(const f32x4*)(p + c0 + 4);
#pragma unroll
    for (int j = 0; j < 8; ++j) {
      float x = (j < 4) ? a[j] : b2[j - 4];
      x = (c0 + j <= i) ? x : -3.4e38f;
      v[j] = x;
      m = fmaxf(m, x);
    }
  } else {
#pragma unroll
    for (int j = 0; j < 8; ++j) v[j] = 0.f;
  }
#pragma unroll
  for (int off = 32; off; off >>= 1) m = fmaxf(m, __shfl_xor(m, off));
  float s = 0.f;
  if (c0 <= i) {
#pragma unroll
    for (int j = 0; j < 8; ++j) {
      float e = (c0 + j <= i) ? expf(v[j] - m) : 0.f;
      v[j] = e;
      s += e;
    }
  }
#pragma unroll
  for (int off = 32; off; off >>= 1) s += __shfl_xor(s, off);
  float inv = 1.f / s;
  if (c0 <= (i | 63)) {
    u16 hh[8], ll[8];
#pragma unroll
    for (int j = 0; j < 8; ++j) {
      float e = (c0 <= i) ? v[j] * inv : 0.f;
      u16 h = f2bf(e);
      hh[j] = h;
      ll[j] = f2bf(e - bf2f(h));
    }
    *(short8*)(ph + base + c0) = *(short8*)hh;
    *(short8*)(pl + base + c0) = *(short8*)ll;
  }
}

// ---------------------------------------------------------------------------
// FUSED: LayerNorm(xh+xl+proj) -> {ctxf, catA[:,0:512]} then router argmax,
// top-4 over 128 keys, memory stream -> {msf, catA[:,512:1024]}.
// ---------------------------------------------------------------------------
__global__ __launch_bounds__(128) void ln_route_k(
    const u16* __restrict__ xh, const u16* __restrict__ xl,
    const float* __restrict__ proj,
    const float* __restrict__ g, const float* __restrict__ b,
    const float* __restrict__ Wr, const float* __restrict__ keys,
    const float* __restrict__ valsm,
    float* __restrict__ ctxf, u16* __restrict__ catA, float* __restrict__ msf)
{
  const int t = blockIdx.x;
  const int tid = threadIdx.x;
  __shared__ float sctx[D_];
  __shared__ float red2[4];
  __shared__ float spart[CAP_];
  __shared__ float sred2[2][64];
  __shared__ int s_route;
  __shared__ int sidx[4];
  __shared__ float sw[4];

  const int c = tid * 4;
  ull hv = *(const ull*)(xh + (long)t * D_ + c);
  ull lv = *(const ull*)(xl + (long)t * D_ + c);
  f32x4 pv = *(const f32x4*)(proj + (long)t * D_ + c);
  float v0 = bf2f((u16)(hv)) + bf2f((u16)(lv)) + pv[0];
  float v1 = bf2f((u16)(hv >> 16)) + bf2f((u16)(lv >> 16)) + pv[1];
  float v2 = bf2f((u16)(hv >> 32)) + bf2f((u16)(lv >> 32)) + pv[2];
  float v3 = bf2f((u16)(hv >> 48)) + bf2f((u16)(lv >> 48)) + pv[3];
  float s = v0 + v1 + v2 + v3;
  float q = v0 * v0 + v1 * v1 + v2 * v2 + v3 * v3;
#pragma unroll
  for (int off = 32; off; off >>= 1) { s += __shfl_xor(s, off); q += __shfl_xor(q, off); }
  const int wave = tid >> 6, lane = tid & 63;
  if (lane == 0) { red2[wave] = s; red2[2 + wave] = q; }
  __syncthreads();
  s = red2[0] + red2[1];
  q = red2[2] + red2[3];
  float mu = s * (1.f / 512.f);
  float var = q * (1.f / 512.f) - mu * mu;
  float rs = rsqrtf(var + 1e-5f);
  f32x4 gv = *(const f32x4*)(g + c);
  f32x4 bv = *(const f32x4*)(b + c);
  f32x4 of;
  of[0] = (v0 - mu) * rs * gv[0] + bv[0];
  of[1] = (v1 - mu) * rs * gv[1] + bv[1];
  of[2] = (v2 - mu) * rs * gv[2] + bv[2];
  of[3] = (v3 - mu) * rs * gv[3] + bv[3];
  *(f32x4*)(ctxf + (long)t * D_ + c) = of;
  ((f32x4*)sctx)[tid] = of;
  {
    u16 hh[4];
#pragma unroll
    for (int j = 0; j < 4; ++j) hh[j] = f2bf(of[j]);
    *(ull*)(catA + (long)t * 1024 + c) = *(ull*)hh;
  }
  __syncthreads();

  {
    const int cc = tid & 63, half = tid >> 6;
    float accr = 0.f;
    const float* cp = sctx + half * 256;
    const float* wp = Wr + (long)(half * 256) * NSHARD_ + cc;
    for (int d = 0; d < 256; ++d) accr += cp[d] * wp[(long)d * NSHARD_];
    sred2[half][cc] = accr;
  }
  __syncthreads();
  if (tid < 64) {
    float v = sred2[0][tid] + sred2[1][tid];
    int idx = tid;
#pragma unroll
    for (int off = 32; off; off >>= 1) {
      float ov = __shfl_xor(v, off);
      int oi = __shfl_xor(idx, off);
      if (ov > v || (ov == v && oi < idx)) { v = ov; idx = oi; }
    }
    if (tid == 0) s_route = idx;
  }
  __syncthreads();
  const int route = s_route;

  {
    const float* krow = keys + ((long)route * CAP_ + tid) * D_;
    float sc = 0.f;
    for (int d0 = 0; d0 < D_; d0 += 4) {
      f32x4 kv = *(const f32x4*)(krow + d0);
      sc += sctx[d0] * kv[0] + sctx[d0 + 1] * kv[1] +
            sctx[d0 + 2] * kv[2] + sctx[d0 + 3] * kv[3];
    }
    spart[tid] = sc;
  }
  __syncthreads();

  for (int rep = 0; rep < 4; ++rep) {
    if (tid < 64) {
      float v1r = spart[tid]; int i1 = tid;
      float v2r = spart[tid + 64]; int i2 = tid + 64;
      float v; int idx;
      if (v2r > v1r) { v = v2r; idx = i2; } else { v = v1r; idx = i1; }
#pragma unroll
      for (int off = 32; off; off >>= 1) {
        float ov = __shfl_xor(v, off);
        int oi = __shfl_xor(idx, off);
        if (ov > v || (ov == v && oi < idx)) { v = ov; idx = oi; }
      }
      if (tid == 0) { sidx[rep] = idx; sw[rep] = v; spart[idx] = -3.4e38f; }
    }
    __syncthreads();
  }

  float w0 = sw[0], w1 = sw[1], w2 = sw[2], w3 = sw[3];
  float mx = fmaxf(fmaxf(w0, w1), fmaxf(w2, w3));
  float e0 = expf(w0 - mx), e1 = expf(w1 - mx), e2 = expf(w2 - mx), e3 = expf(w3 - mx);
  float inv = 1.f / (e0 + e1 + e2 + e3);
  float wk[4] = {e0 * inv, e1 * inv, e2 * inv, e3 * inv};

  float a0 = 0, a1 = 0, a2 = 0, a3 = 0;
#pragma unroll
  for (int k = 0; k < 4; ++k) {
    const float* vr = valsm + ((long)route * CAP_ + sidx[k]) * D_ + c;
    f32x4 vv = *(const f32x4*)vr;
    float w = wk[k];
    a0 += w * vv[0]; a1 += w * vv[1]; a2 += w * vv[2]; a3 += w * vv[3];
  }
  f32x4 om; om[0] = a0; om[1] = a1; om[2] = a2; om[3] = a3;
  *(f32x4*)(msf + (long)t * D_ + c) = om;
  u16 ohh[4];
  ohh[0] = f2bf(a0); ohh[1] = f2bf(a1); ohh[2] = f2bf(a2); ohh[3] = f2bf(a3);
  *(ull*)(catA + (long)t * 1024 + 512 + c) = *(ull*)ohh;
}

// ---------------------------------------------------------------------------
extern "C" void kernel_launch(void* const* d_in, const int* in_sizes, int n_in,
                              void* d_out, int out_size, void* d_ws, size_t ws_size,
                              hipStream_t stream) {
  const int*   ids  = (const int*)d_in[0];
  const float* emb  = (const float*)d_in[1];
  const float* Wq   = (const float*)d_in[2];
  const float* Wk   = (const float*)d_in[3];
  const float* Wv   = (const float*)d_in[4];
  const float* Wo   = (const float*)d_in[5];
  const float* ln_g = (const float*)d_in[6];
  const float* ln_b = (const float*)d_in[7];
  const float* Wr   = (const float*)d_in[8];
  const float* mk   = (const float*)d_in[9];
  const float* mv   = (const float*)d_in[10];
  const float* Wgc  = (const float*)d_in[11];
  const float* Wgm  = (const float*)d_in[12];
  const float* bg   = (const float*)d_in[13];
  const float* Wd   = (const float*)d_in[14];
  const float* bd   = (const float*)d_in[15];
  float* out = (float*)d_out;

  char* ws = (char*)d_ws;
  size_t off = 0;
  auto alloc = [&](size_t bytes) -> void* {
    void* p = ws + off;
    off += (bytes + 255) & ~(size_t)255;
    return p;
  };
  u16*   xh     = (u16*)  alloc((size_t)TOK_ * D_ * 2);
  u16*   xl     = (u16*)  alloc((size_t)TOK_ * D_ * 2);
  u16*   wqkvTh = (u16*)  alloc((size_t)3 * D_ * D_ * 2);
  u16*   wqkvTl = (u16*)  alloc((size_t)3 * D_ * D_ * 2);
  u16*   woTh   = (u16*)  alloc((size_t)D_ * D_ * 2);
  u16*   woTl   = (u16*)  alloc((size_t)D_ * D_ * 2);
  u16*   wgT    = (u16*)  alloc((size_t)D_ * 1024 * 2);
  u16*   wdT    = (u16*)  alloc((size_t)D_ * V_ * 2);
  u16*   qkvh   = (u16*)  alloc((size_t)TOK_ * 3 * D_ * 2);
  u16*   qkvl   = (u16*)  alloc((size_t)TOK_ * 3 * D_ * 2);
  u16*   vTh    = (u16*)  alloc((size_t)B_ * H_ * HD_ * S_ * 2);
  u16*   vTl    = (u16*)  alloc((size_t)B_ * H_ * HD_ * S_ * 2);
  float* att    = (float*)alloc((size_t)B_ * H_ * S_ * S_ * 4);
  u16*   ph     = (u16*)  alloc((size_t)B_ * H_ * S_ * S_ * 2);
  u16*   pl     = (u16*)  alloc((size_t)B_ * H_ * S_ * S_ * 2);
  u16*   oh     = (u16*)  alloc((size_t)TOK_ * D_ * 2);
  u16*   ol     = (u16*)  alloc((size_t)TOK_ * D_ * 2);
  float* proj   = (float*)alloc((size_t)TOK_ * D_ * 4);
  float* ctxf   = (float*)alloc((size_t)TOK_ * D_ * 4);
  u16*   catA   = (u16*)  alloc((size_t)TOK_ * 1024 * 2);
  float* msf    = (float*)alloc((size_t)TOK_ * D_ * 4);
  u16*   fused  = (u16*)  alloc((size_t)TOK_ * D_ * 2);

  const long SD  = (long)S_ * D_;
  const long SSq = (long)S_ * S_;
  const long HSS = (long)H_ * S_ * S_;

  // 1) small-weight prep + embed (one launch)
  prep_embed_k<<<1408, 256, 0, stream>>>(
      Wq, Wk, Wv, Wo, Wgc, Wgm,
      wqkvTh, wqkvTl, woTh, woTl, wgT, ids, emb, xh, xl);

  // 2) qkv = x @ [Wq|Wk|Wv]  (split pair out)
  {
    dim3 g(1536 / 64, TOK_ / 64, 1);
    gemm_bt<3, false, 1, false><<<g, 256, 0, stream>>>(
        xh, xl, D_, 0, 0, wqkvTh, wqkvTl, D_, 0, 0,
        qkvh, qkvl, 1536, 0, 0, D_, 1, 1.f);
  }

  // 3) vT per-head transpose
  {
    dim3 g(S_ / 64, B_ * H_, 1);
    v_transpose_k<<<g, 256, 0, stream>>>(qkvh, qkvl, vTh, vTl);
  }

  // 4) MEGA: qkt (z<32) + Wd prep tiles (z>=32, overlapped — result needed
  //    only by the logits GEMM)
  {
    dim3 g(8, 8, 32 + 63);
    qkt_wd_k<<<g, 256, 0, stream>>>(qkvh, qkvl, att, Wd, wdT);
  }

  // 5) causal softmax -> split pair
  softmax_causal_k<<<B_ * H_ * S_, 64, 0, stream>>>(att, ph, pl);

  // 6) o = p @ v  (causal K-limit, split pair out)
  {
    dim3 g(1, S_ / 64, B_ * H_);
    gemm_bt<3, false, 1, true><<<g, 256, 0, stream>>>(
        ph, pl, S_, HSS, SSq,
        vTh, vTl, S_, (long)H_ * HD_ * S_, (long)HD_ * S_,
        oh, ol, D_, SD, HD_,
        S_, H_, 1.f);
  }

  // 7) proj = o @ Wo
  {
    dim3 g(D_ / 64, TOK_ / 64, 1);
    gemm_bt<3, false, 0, false><<<g, 256, 0, stream>>>(
        oh, ol, D_, 0, 0, woTh, woTl, D_, 0, 0,
        proj, nullptr, D_, 0, 0, D_, 1, 1.f);
  }

  // 8) FUSED: LN + routing + memory stream
  ln_route_k<<<TOK_, 128, 0, stream>>>(
      xh, xl, proj, ln_g, ln_b, Wr, mk, mv, ctxf, catA, msf);

  // 9) FUSED: gate GEMM (K=1024) + sigmoid-mix epilogue -> fused bf16
  {
    dim3 g(D_ / 64, TOK_ / 64, 1);
    gate_gemm_k<<<g, 256, 0, stream>>>(catA, wgT, bg, ctxf, msf, fused);
  }

  // 10) logits = fused @ wdT^T + bd
  logits_gemm_bk32_k<<<2000, 512, 0, stream>>>(fused, wdT, bd, out);
}